// Round 5
// baseline (1878.365 us; speedup 1.0000x reference)
//
#include <hip/hip_runtime.h>

#define D 128
#define RNUM 7
#define GNUM 64
#define LAYERS 3
#define MBLK 16          // dest nodes per block in layer kernel
#define SEG_SHIFT 3      // segments = node*8 + rel (slot 7 empty)

// ---------- x0[n,:] = emb[unit_type[n],:] ----------
__global__ __launch_bounds__(256) void init_x_kernel(const int* __restrict__ ut,
    const float* __restrict__ emb, float* __restrict__ x, int n) {
  int tid = blockIdx.x * 256 + threadIdx.x;
  int nidx = tid >> 5, q = tid & 31;
  if (nidx >= n) return;
  ((float4*)x)[(size_t)nidx * 32 + q] = ((const float4*)emb)[(size_t)ut[nidx] * 32 + q];
}

// ---------- CSR build: histogram over (dest node, rel) segments ----------
__global__ __launch_bounds__(256) void hist_kernel(const int* __restrict__ nout,
    const int* __restrict__ rel, int* __restrict__ hist, int ne) {
  int e = blockIdx.x * 256 + threadIdx.x;
  if (e >= ne) return;
  atomicAdd(&hist[(nout[e] << SEG_SHIFT) | rel[e]], 1);
}

// ---------- scan stage 1: per-block (1024 elems) exclusive scan + totals ----------
__global__ __launch_bounds__(256) void scan1_kernel(const int* __restrict__ hist,
    int* __restrict__ row_ptr, int* __restrict__ partials, int nseg) {
  __shared__ int buf[256];
  const int t = threadIdx.x;
  const int base = blockIdx.x * 1024 + t * 4;
  int v0 = 0, v1 = 0, v2 = 0, v3 = 0;
  if (base + 3 < nseg) {
    int4 h4 = *(const int4*)&hist[base];
    v0 = h4.x; v1 = h4.y; v2 = h4.z; v3 = h4.w;
  } else {
    if (base + 0 < nseg) v0 = hist[base + 0];
    if (base + 1 < nseg) v1 = hist[base + 1];
    if (base + 2 < nseg) v2 = hist[base + 2];
    if (base + 3 < nseg) v3 = hist[base + 3];
  }
  int tsum = v0 + v1 + v2 + v3;
  buf[t] = tsum;
  __syncthreads();
  for (int off = 1; off < 256; off <<= 1) {
    int add = (t >= off) ? buf[t - off] : 0;
    __syncthreads();
    buf[t] += add;
    __syncthreads();
  }
  int incl = buf[t];
  int e0 = incl - tsum;   // block-local exclusive
  int e1 = e0 + v0, e2 = e1 + v1, e3 = e2 + v2;
  if (base + 0 < nseg) row_ptr[base + 0] = e0;
  if (base + 1 < nseg) row_ptr[base + 1] = e1;
  if (base + 2 < nseg) row_ptr[base + 2] = e2;
  if (base + 3 < nseg) row_ptr[base + 3] = e3;
  if (t == 255) partials[blockIdx.x] = incl;
}

// ---------- scan stage 2: exclusive scan of block totals (single block) ----------
__global__ __launch_bounds__(256) void scan2_kernel(int* __restrict__ partials, int nb) {
  __shared__ int buf[256];
  __shared__ int carry_s;
  const int t = threadIdx.x;
  if (t == 0) carry_s = 0;
  __syncthreads();
  for (int c0 = 0; c0 < nb; c0 += 256) {
    int i = c0 + t;
    int v = (i < nb) ? partials[i] : 0;
    buf[t] = v;
    __syncthreads();
    for (int off = 1; off < 256; off <<= 1) {
      int add = (t >= off) ? buf[t - off] : 0;
      __syncthreads();
      buf[t] += add;
      __syncthreads();
    }
    int incl = buf[t];
    int excl = incl - v + carry_s;
    if (i < nb) partials[i] = excl;
    __syncthreads();              // everyone has read carry_s
    if (t == 255) carry_s += incl;
    __syncthreads();
  }
}

// ---------- scan stage 3: add block offsets, init cursor ----------
__global__ __launch_bounds__(256) void scan3_kernel(int* __restrict__ row_ptr,
    int* __restrict__ cursor, const int* __restrict__ partials, int nseg, int ne) {
  int i = blockIdx.x * 256 + threadIdx.x;
  if (i < nseg) {
    int v = row_ptr[i] + partials[i >> 10];
    row_ptr[i] = v;
    cursor[i] = v;
  }
  if (i == 0) row_ptr[nseg] = ne;
}

// ---------- fill CSR edge records: (node_in | rel<<20, ew) ----------
__global__ __launch_bounds__(256) void fill_kernel(const int* __restrict__ nin,
    const int* __restrict__ nout, const int* __restrict__ rel,
    const float* __restrict__ ew, int* __restrict__ cursor,
    int2* __restrict__ erec, int ne) {
  int e = blockIdx.x * 256 + threadIdx.x;
  if (e >= ne) return;
  int r = rel[e];
  int pos = atomicAdd(&cursor[(nout[e] << SEG_SHIFT) | r], 1);
  erec[pos] = make_int2(nin[e] | (r << 20), __float_as_int(ew[e]));
}

__device__ __forceinline__ void add4(float4& d, const float4& s) {
  d.x += s.x; d.y += s.y; d.z += s.z; d.w += s.w;
}
__device__ __forceinline__ void fma4(float4& d, float s, const float4& v) {
  d.x += s * v.x; d.y += s * v.y; d.z += s * v.z; d.w += s * v.w;
}
__device__ __forceinline__ void flush_bank(float4* bank, int c, const float4& a) {
  switch (c) {
    case 0: add4(bank[0], a); break;
    case 1: add4(bank[1], a); break;
    case 2: add4(bank[2], a); break;
    case 3: add4(bank[3], a); break;
    case 4: add4(bank[4], a); break;
    case 5: add4(bank[5], a); break;
    default: add4(bank[6], a); break;
  }
}

// ---------- fused layer ----------
// Per block: 16 dest nodes. Each half-wave walks its 2 nodes' FULL contiguous
// edge ranges (rel-sorted) in flat unrolled-x4 loops, accumulating into a
// running float4 and flushing on rel-change into 7 register banks per node.
// Then per rel: dump banks to 8KB LDS tile, block mini-GEMM vs W_r.
__global__ __launch_bounds__(256) void layer_kernel(
    const float* __restrict__ x, const int2* __restrict__ erec,
    const int* __restrict__ row_ptr,
    const float* __restrict__ Wrel, const float* __restrict__ brel,
    const float* __restrict__ Wloop, const float* __restrict__ bloop,
    float* __restrict__ h, int n) {
  __shared__ float tile[MBLK][D];   // 16 x 128 fp32 = 8 KB
  const int t = threadIdx.x;
  const int m0 = blockIdx.x * MBLK;
  const float4* X4 = (const float4*)x;
  const int hw = t >> 5;         // half-wave id 0..7
  const int lane = t & 31;       // float4 lane within 128-float row
  const int nA = m0 + hw * 2;
  const int nB = nA + 1;

  float4 bankA[RNUM], bankB[RNUM];
#pragma unroll
  for (int r = 0; r < RNUM; ++r) {
    bankA[r] = make_float4(0.f, 0.f, 0.f, 0.f);
    bankB[r] = make_float4(0.f, 0.f, 0.f, 0.f);
  }

  auto aggregate = [&](int node, float4* bank) {
    if (node >= n) return;
    int s = row_ptr[node << SEG_SHIFT];
    int e = row_ptr[(node + 1) << SEG_SHIFT];
    int cur = 0;
    float4 a = make_float4(0.f, 0.f, 0.f, 0.f);
    int j = s;
    for (; j + 3 < e; j += 4) {
      int2 r0 = erec[j];
      int2 r1 = erec[j + 1];
      int2 r2 = erec[j + 2];
      int2 r3 = erec[j + 3];
      float4 v0 = X4[(size_t)(r0.x & 0xFFFFF) * 32 + lane];
      float4 v1 = X4[(size_t)(r1.x & 0xFFFFF) * 32 + lane];
      float4 v2 = X4[(size_t)(r2.x & 0xFFFFF) * 32 + lane];
      float4 v3 = X4[(size_t)(r3.x & 0xFFFFF) * 32 + lane];
      int q0 = r0.x >> 20, q1 = r1.x >> 20, q2 = r2.x >> 20, q3 = r3.x >> 20;
      float w0 = __int_as_float(r0.y), w1 = __int_as_float(r1.y);
      float w2 = __int_as_float(r2.y), w3 = __int_as_float(r3.y);
      if (q0 != cur) { flush_bank(bank, cur, a); a = make_float4(0.f,0.f,0.f,0.f); cur = q0; }
      fma4(a, w0, v0);
      if (q1 != cur) { flush_bank(bank, cur, a); a = make_float4(0.f,0.f,0.f,0.f); cur = q1; }
      fma4(a, w1, v1);
      if (q2 != cur) { flush_bank(bank, cur, a); a = make_float4(0.f,0.f,0.f,0.f); cur = q2; }
      fma4(a, w2, v2);
      if (q3 != cur) { flush_bank(bank, cur, a); a = make_float4(0.f,0.f,0.f,0.f); cur = q3; }
      fma4(a, w3, v3);
    }
    for (; j < e; ++j) {
      int2 r0 = erec[j];
      float4 v0 = X4[(size_t)(r0.x & 0xFFFFF) * 32 + lane];
      int q0 = r0.x >> 20;
      float w0 = __int_as_float(r0.y);
      if (q0 != cur) { flush_bank(bank, cur, a); a = make_float4(0.f,0.f,0.f,0.f); cur = q0; }
      fma4(a, w0, v0);
    }
    flush_bank(bank, cur, a);
  };

  aggregate(nA, bankA);
  aggregate(nB, bankB);

  // --- transform: per rel, dump banks to tile, mini-GEMM vs W_r ---
  const int tc = t & 31;         // col group (4 cols as float4)
  const int tr = t >> 5;         // row group
  const int ra = tr * 2, rb = ra + 1;
  const int ga = m0 + ra, gb = ga + 1;
  float4 acc0 = make_float4(0.f, 0.f, 0.f, 0.f);
  float4 acc1 = make_float4(0.f, 0.f, 0.f, 0.f);
  const float4* Wr4 = (const float4*)Wrel;   // (R*D) x 32 float4

#pragma unroll
  for (int r = 0; r < RNUM; ++r) {
    if (r) __syncthreads();      // previous gemm's tile reads complete
    *(float4*)&tile[hw * 2 + 0][lane * 4] = bankA[r];
    *(float4*)&tile[hw * 2 + 1][lane * 4] = bankB[r];
    __syncthreads();
    for (int k = 0; k < D; k += 4) {
      float4 a0 = *(const float4*)&tile[ra][k];
      float4 a1 = *(const float4*)&tile[rb][k];
#pragma unroll
      for (int kk = 0; kk < 4; ++kk) {
        float4 w = Wr4[(size_t)(r * D + k + kk) * 32 + tc];
        float e0 = (kk == 0) ? a0.x : (kk == 1) ? a0.y : (kk == 2) ? a0.z : a0.w;
        float e1 = (kk == 0) ? a1.x : (kk == 1) ? a1.y : (kk == 2) ? a1.z : a1.w;
        fma4(acc0, e0, w);
        fma4(acc1, e1, w);
      }
    }
  }

  // --- self-loop term ---
  const float4* Wl4 = (const float4*)Wloop;   // 128 x 32 float4
  const bool ok0 = ga < n, ok1 = gb < n;
  for (int k = 0; k < D; k += 4) {
    float4 a0 = ok0 ? X4[(size_t)ga * 32 + (k >> 2)] : make_float4(0, 0, 0, 0);
    float4 a1 = ok1 ? X4[(size_t)gb * 32 + (k >> 2)] : make_float4(0, 0, 0, 0);
#pragma unroll
    for (int kk = 0; kk < 4; ++kk) {
      float4 w = Wl4[(size_t)(k + kk) * 32 + tc];
      float e0 = (kk == 0) ? a0.x : (kk == 1) ? a0.y : (kk == 2) ? a0.z : a0.w;
      float e1 = (kk == 0) ? a1.x : (kk == 1) ? a1.y : (kk == 2) ? a1.z : a1.w;
      fma4(acc0, e0, w);
      fma4(acc1, e1, w);
    }
  }

  float4 br = ((const float4*)brel)[tc];
  float4 bl = ((const float4*)bloop)[tc];
  float4 bias = make_float4(br.x + bl.x, br.y + bl.y, br.z + bl.z, br.w + bl.w);

  if (ok0) {
    float4 o;
    o.x = fmaxf(acc0.x + bias.x, 0.f); o.y = fmaxf(acc0.y + bias.y, 0.f);
    o.z = fmaxf(acc0.z + bias.z, 0.f); o.w = fmaxf(acc0.w + bias.w, 0.f);
    ((float4*)h)[(size_t)ga * 32 + tc] = o;
  }
  if (ok1) {
    float4 o;
    o.x = fmaxf(acc1.x + bias.x, 0.f); o.y = fmaxf(acc1.y + bias.y, 0.f);
    o.z = fmaxf(acc1.z + bias.z, 0.f); o.w = fmaxf(acc1.w + bias.w, 0.f);
    ((float4*)h)[(size_t)gb * 32 + tc] = o;
  }
}

// ---------- graph pooling (node2graph sorted) ----------
__global__ __launch_bounds__(256) void pool_kernel(const float* __restrict__ x,
    const int* __restrict__ n2g, float* __restrict__ gf, int n) {
  int d = threadIdx.x & 127;
  int sub = threadIdx.x >> 7;
  int n0 = (blockIdx.x * 2 + sub) * 128;
  int nend = n0 + 128;
  if (nend > n) nend = n;
  float acc = 0.f;
  int gcur = -1;
  for (int i = n0; i < nend; ++i) {
    int g = n2g[i];
    if (g != gcur) {
      if (gcur >= 0) atomicAdd(&gf[gcur * D + d], acc);
      gcur = g;
      acc = 0.f;
    }
    acc += x[(size_t)i * D + d];
  }
  if (gcur >= 0) atomicAdd(&gf[gcur * D + d], acc);
}

extern "C" void kernel_launch(void* const* d_in, const int* in_sizes, int n_in,
                              void* d_out, int out_size, void* d_ws, size_t ws_size,
                              hipStream_t stream) {
  const int*   unit_type  = (const int*)d_in[0];
  const int*   node_in    = (const int*)d_in[1];
  const int*   node_out   = (const int*)d_in[2];
  const int*   relation   = (const int*)d_in[3];
  const float* edge_w     = (const float*)d_in[4];
  const int*   node2graph = (const int*)d_in[5];
  const float* emb        = (const float*)d_in[6];
  const float* W_rel      = (const float*)d_in[7];
  const float* b_rel      = (const float*)d_in[8];
  const float* W_loop     = (const float*)d_in[9];
  const float* b_loop     = (const float*)d_in[10];

  const int n  = in_sizes[0];
  const int ne = in_sizes[1];
  float* out = (float*)d_out;

  const int nseg = n << SEG_SHIFT;
  const int nb   = (nseg + 1023) / 1024;

  // workspace layout
  const size_t ND = (size_t)n * D;
  float* x0       = (float*)d_ws;
  float* x1       = x0 + ND;
  int2*  erec     = (int2*)(x1 + ND);
  int*   hist     = (int*)(erec + ne);
  int*   row_ptr  = hist + nseg;
  int*   cursor   = row_ptr + ((nseg + 4) & ~3);
  int*   partials = cursor + nseg;

  hipMemsetAsync(d_out, 0, (size_t)GNUM * D * sizeof(float), stream);
  hipMemsetAsync(hist, 0, (size_t)nseg * sizeof(int), stream);

  const int eblocks = (ne + 255) / 256;
  hist_kernel<<<eblocks, 256, 0, stream>>>(node_out, relation, hist, ne);
  scan1_kernel<<<nb, 256, 0, stream>>>(hist, row_ptr, partials, nseg);
  scan2_kernel<<<1, 256, 0, stream>>>(partials, nb);
  scan3_kernel<<<(nseg + 255) / 256, 256, 0, stream>>>(row_ptr, cursor, partials, nseg, ne);
  fill_kernel<<<eblocks, 256, 0, stream>>>(node_in, node_out, relation, edge_w,
                                           cursor, erec, ne);

  const int nq = n * 32;
  init_x_kernel<<<(nq + 255) / 256, 256, 0, stream>>>(unit_type, emb, x0, n);

  const int lblocks = (n + MBLK - 1) / MBLK;
  float* cur = x0;
  for (int i = 0; i < LAYERS; ++i) {
    float* nxt = (i == LAYERS - 1) ? (out + GNUM * D) : (cur == x0 ? x1 : x0);
    layer_kernel<<<lblocks, 256, 0, stream>>>(
        cur, erec, row_ptr,
        W_rel + (size_t)i * RNUM * D * D, b_rel + (size_t)i * D,
        W_loop + (size_t)i * D * D, b_loop + (size_t)i * D,
        nxt, n);
    cur = nxt;
  }

  pool_kernel<<<(n + 255) / 256, 256, 0, stream>>>(cur, node2graph, out, n);
}